// Round 5
// baseline (823.230 us; speedup 1.0000x reference)
//
#include <hip/hip_runtime.h>
#include <math.h>

#define BATCH 16384
#define HDIM  256
#define DIN   228    // 128 latent + 100 cond
#define DOUTN 2100
#define NGRP  200
#define THETA 2e-3   // top-2 gap below this -> f64 recompute
#define FCAP  65536

typedef unsigned short u16;
typedef __attribute__((ext_vector_type(8))) short bf16x8;
typedef __attribute__((ext_vector_type(4))) float f32x4;
typedef __attribute__((ext_vector_type(8))) unsigned short u16x8;
typedef __attribute__((ext_vector_type(4))) unsigned short u16x4;

// RNE split: x = hi + lo (both bf16)
__device__ __forceinline__ void split_bf16(float x, u16& hi, u16& lo) {
    unsigned int u = __float_as_uint(x);
    unsigned int r = (u + 0x7fffu + ((u >> 16) & 1u)) >> 16;
    hi = (u16)r;
    const float hf = __uint_as_float(r << 16);
    const float l = x - hf;
    unsigned int u2 = __float_as_uint(l);
    unsigned int r2 = (u2 + 0x7fffu + ((u2 >> 16) & 1u)) >> 16;
    lo = (u16)r2;
}

// ---------------------------------------------------------------------------
// R2-PROVEN f32 tiled GEMM (gated). 128x128, KT=16, 256 thr, 8x8 microtile.
// MODE 0: h1 = i0 @ W1 + b1   MODE 1: h2 = [bnrelu(h1), i0] @ W2 + b2
// MODE 2: x = bnrelu(h2) @ Wout + bout   (repair path, gated on *gate != 0)
// ---------------------------------------------------------------------------
template <int MODE>
__global__ __launch_bounds__(256) void gemm_f32(
    const float* __restrict__ z,   const float* __restrict__ c,
    const float* __restrict__ hin,
    const float* __restrict__ scf, const float* __restrict__ shf,
    const float* __restrict__ W,   const float* __restrict__ bias,
    float* __restrict__ out,       const int* __restrict__ gate)
{
    if (gate && *gate == 0) return;

    constexpr int K  = (MODE == 0) ? DIN : (MODE == 1) ? (HDIM + DIN) : HDIM;
    constexpr int N  = (MODE == 2) ? DOUTN : HDIM;
    constexpr int KT = 16, BM = 128, BN = 128;

    __shared__ float Ash[KT][BM + 4];
    __shared__ float Bsh[KT][BN + 4];

    const int tid  = threadIdx.x;
    const int row0 = blockIdx.y * BM;
    const int n0   = blockIdx.x * BN;
    const int tx   = tid & 15, ty = tid >> 4;
    const int arow = tid >> 1, ahalf = (tid & 1) * 8;
    const int bkk  = tid >> 4, bc = (tid & 15) * 8;
    const bool nfast = (n0 + BN <= N);

    float acc[2][2][4][4] = {};

    for (int kt = 0; kt < K; kt += KT) {
        __syncthreads();
        #pragma unroll
        for (int q = 0; q < 8; ++q) {
            const int gk = kt + ahalf + q;
            float v = 0.f;
            if (MODE == 0) {
                if (gk < DIN)
                    v = (gk < 128) ? z[(size_t)(row0 + arow) * 128 + gk]
                                   : c[(size_t)(row0 + arow) * 100 + gk - 128];
            } else if (MODE == 1) {
                if (gk < HDIM) {
                    const float h = hin[(size_t)(row0 + arow) * HDIM + gk];
                    const float s = fmaf(h, scf[gk], shf[gk]);
                    v = s > 0.f ? s : 0.f;
                } else if (gk < HDIM + DIN) {
                    const int k2 = gk - HDIM;
                    v = (k2 < 128) ? z[(size_t)(row0 + arow) * 128 + k2]
                                   : c[(size_t)(row0 + arow) * 100 + k2 - 128];
                }
            } else {
                const float h = hin[(size_t)(row0 + arow) * HDIM + gk];
                const float s = fmaf(h, scf[gk], shf[gk]);
                v = s > 0.f ? s : 0.f;
            }
            Ash[ahalf + q][arow] = v;
        }
        {
            const int gk = kt + bkk;
            if (nfast && gk < K) {
                const float4 w0 = *reinterpret_cast<const float4*>(&W[(size_t)gk * N + n0 + bc]);
                const float4 w1 = *reinterpret_cast<const float4*>(&W[(size_t)gk * N + n0 + bc + 4]);
                *reinterpret_cast<float4*>(&Bsh[bkk][bc])     = w0;
                *reinterpret_cast<float4*>(&Bsh[bkk][bc + 4]) = w1;
            } else {
                #pragma unroll
                for (int q = 0; q < 8; ++q) {
                    const int gn = n0 + bc + q;
                    Bsh[bkk][bc + q] = (gk < K && gn < N) ? W[(size_t)gk * N + gn] : 0.f;
                }
            }
        }
        __syncthreads();
        #pragma unroll
        for (int kk = 0; kk < KT; ++kk) {
            float a[2][4], b[2][4];
            *reinterpret_cast<float4*>(a[0]) = *reinterpret_cast<const float4*>(&Ash[kk][ty * 4]);
            *reinterpret_cast<float4*>(a[1]) = *reinterpret_cast<const float4*>(&Ash[kk][64 + ty * 4]);
            *reinterpret_cast<float4*>(b[0]) = *reinterpret_cast<const float4*>(&Bsh[kk][tx * 4]);
            *reinterpret_cast<float4*>(b[1]) = *reinterpret_cast<const float4*>(&Bsh[kk][64 + tx * 4]);
            #pragma unroll
            for (int rb = 0; rb < 2; ++rb)
                #pragma unroll
                for (int cb = 0; cb < 2; ++cb)
                    #pragma unroll
                    for (int i = 0; i < 4; ++i)
                        #pragma unroll
                        for (int j = 0; j < 4; ++j)
                            acc[rb][cb][i][j] = fmaf(a[rb][i], b[cb][j], acc[rb][cb][i][j]);
        }
    }

    #pragma unroll
    for (int rb = 0; rb < 2; ++rb)
        #pragma unroll
        for (int i = 0; i < 4; ++i) {
            const size_t row = row0 + rb * 64 + ty * 4 + i;
            #pragma unroll
            for (int cb = 0; cb < 2; ++cb) {
                const int n = n0 + cb * 64 + tx * 4;
                if (nfast) {
                    float4 r;
                    r.x = acc[rb][cb][i][0] + bias[n + 0];
                    r.y = acc[rb][cb][i][1] + bias[n + 1];
                    r.z = acc[rb][cb][i][2] + bias[n + 2];
                    r.w = acc[rb][cb][i][3] + bias[n + 3];
                    *reinterpret_cast<float4*>(&out[row * N + n]) = r;
                } else {
                    #pragma unroll
                    for (int j = 0; j < 4; ++j)
                        if (n + j < N) out[row * N + n + j] = acc[rb][cb][i][j] + bias[n + j];
                }
            }
        }
}

// ---------------------------------------------------------------------------
// BN stats (R2-proven): fused column sum+sumsq, f64, 256 blocks x 64 rows.
// ---------------------------------------------------------------------------
__global__ __launch_bounds__(256) void colsum2_k(const float* __restrict__ h,
                                                 double* __restrict__ part)
{
    const int col = threadIdx.x;
    const size_t b0 = (size_t)blockIdx.x * 64;
    double s = 0.0, q = 0.0;
    for (int r = 0; r < 64; ++r) {
        const double v = (double)h[(b0 + r) * HDIM + col];
        s += v;
        q = fma(v, v, q);
    }
    part[(size_t)blockIdx.x * 512 + col]       = s;
    part[(size_t)blockIdx.x * 512 + 256 + col] = q;
}

__global__ __launch_bounds__(256) void fin_k(const double* __restrict__ part,
                                             const float* __restrict__ g,
                                             const float* __restrict__ be,
                                             double* __restrict__ sc64,
                                             double* __restrict__ sh64,
                                             float* __restrict__ scf,
                                             float* __restrict__ shf)
{
    const int col = threadIdx.x;
    double s = 0.0, q = 0.0;
    for (int i = 0; i < 256; ++i) {
        s += part[(size_t)i * 512 + col];
        q += part[(size_t)i * 512 + 256 + col];
    }
    const double mu    = s / (double)BATCH;
    const double var   = q / (double)BATCH - mu * mu;
    const double rs    = 1.0 / sqrt(var + 1e-5);
    const double scale = rs * (double)g[col];
    const double shift = (double)be[col] - mu * scale;
    sc64[col] = scale;  sh64[col] = shift;
    scf[col]  = (float)scale;  shf[col] = (float)shift;
}

// ---------------------------------------------------------------------------
// BN+relu+split h2 -> A2 planes [B][256] bf16 hi/lo.
// ---------------------------------------------------------------------------
__global__ __launch_bounds__(256) void bnsplit_k(const float* __restrict__ h,
                                                 const float* __restrict__ scf,
                                                 const float* __restrict__ shf,
                                                 u16* __restrict__ hi, u16* __restrict__ lo)
{
    const int t = blockIdx.x * 256 + threadIdx.x;   // BATCH*64
    const int row = t >> 6, c4 = (t & 63) * 4;
    const float4 v = *(const float4*)&h[(size_t)row * 256 + c4];
    const float vv[4] = {v.x, v.y, v.z, v.w};
    u16x4 H, L;
    #pragma unroll
    for (int j = 0; j < 4; ++j) {
        float s = fmaf(vv[j], scf[c4 + j], shf[c4 + j]);
        s = fmaxf(s, 0.f);
        u16 hh, ll; split_bf16(s, hh, ll);
        H[j] = hh; L[j] = ll;
    }
    *(u16x4*)&hi[(size_t)row * 256 + c4] = H;
    *(u16x4*)&lo[(size_t)row * 256 + c4] = L;
}

// ---------------------------------------------------------------------------
// Transpose + split Wout: [256][2100] f32 -> planes [2176][256] bf16.
// ---------------------------------------------------------------------------
__global__ __launch_bounds__(256) void splitW_k(const float* __restrict__ W,
                                                int K0, int N0, int Kpad, int Npad,
                                                u16* __restrict__ Whi, u16* __restrict__ Wlo)
{
    const int n = blockIdx.x * 256 + threadIdx.x;
    if (n >= Npad) return;
    for (int kb = 0; kb < Kpad; kb += 8) {
        u16x8 H, L;
        #pragma unroll
        for (int j = 0; j < 8; ++j) {
            const int k = kb + j;
            const float x = (k < K0 && n < N0) ? W[(size_t)k * N0 + n] : 0.f;
            u16 h, l; split_bf16(x, h, l);
            H[j] = h; L[j] = l;
        }
        *(u16x8*)&Whi[(size_t)n * Kpad + kb] = H;
        *(u16x8*)&Wlo[(size_t)n * Kpad + kb] = L;
    }
}

// ---------------------------------------------------------------------------
// bf16x3 MFMA GEMM (UNDER TEST): A [M][256], B [2176][256], 128x128 tile.
// Reg-staged LDS, chunk-XOR swizzle identical on write and read.
// ---------------------------------------------------------------------------
template <int K>
__global__ __launch_bounds__(256) void gemm_bf16x3(
    const u16* __restrict__ Ahi, const u16* __restrict__ Alo,
    const u16* __restrict__ Bhi, const u16* __restrict__ Blo,
    const float* __restrict__ bias, float* __restrict__ out, int Nout)
{
    __shared__ __align__(16) u16 lds[4 * 128 * 64];
    u16* Ah = lds;
    u16* Al = lds + 8192;
    u16* Bh = lds + 16384;
    u16* Bl = lds + 24576;

    const int tid  = threadIdx.x;
    const int lane = tid & 63;
    const int w    = tid >> 6;
    const int wm   = (w >> 1) * 64, wn = (w & 1) * 64;
    const int row0 = blockIdx.y * 128, n0 = blockIdx.x * 128;

    const u16* gAh = Ahi + (size_t)row0 * K;
    const u16* gAl = Alo + (size_t)row0 * K;
    const u16* gBh = Bhi + (size_t)n0 * K;
    const u16* gBl = Blo + (size_t)n0 * K;

    f32x4 acc[4][4] = {};

    for (int kc = 0; kc < K; kc += 64) {
        __syncthreads();
        #pragma unroll
        for (int q = 0; q < 4; ++q) {
            const int cidx = q * 256 + tid;
            const int r = cidx >> 3, s = cidx & 7;
            const size_t go = (size_t)r * K + kc + s * 8;
            const int lo = r * 64 + ((s ^ (r & 7)) * 8);
            const u16x8 va = *(const u16x8*)(gAh + go);
            const u16x8 vb = *(const u16x8*)(gAl + go);
            const u16x8 vc = *(const u16x8*)(gBh + go);
            const u16x8 vd = *(const u16x8*)(gBl + go);
            *(u16x8*)(Ah + lo) = va;
            *(u16x8*)(Al + lo) = vb;
            *(u16x8*)(Bh + lo) = vc;
            *(u16x8*)(Bl + lo) = vd;
        }
        __syncthreads();

        #pragma unroll
        for (int ks = 0; ks < 2; ++ks) {
            bf16x8 ah[4], al[4], bh[4], bl[4];
            const int o = (ks * 4 + (lane >> 4)) * 8;
            #pragma unroll
            for (int mf = 0; mf < 4; ++mf) {
                const int r = wm + mf * 16 + (lane & 15);
                const int off = r * 64 + (o ^ ((r & 7) * 8));
                ah[mf] = *(const bf16x8*)(Ah + off);
                al[mf] = *(const bf16x8*)(Al + off);
            }
            #pragma unroll
            for (int nf = 0; nf < 4; ++nf) {
                const int r = wn + nf * 16 + (lane & 15);
                const int off = r * 64 + (o ^ ((r & 7) * 8));
                bh[nf] = *(const bf16x8*)(Bh + off);
                bl[nf] = *(const bf16x8*)(Bl + off);
            }
            #pragma unroll
            for (int mf = 0; mf < 4; ++mf)
                #pragma unroll
                for (int nf = 0; nf < 4; ++nf) {
                    acc[mf][nf] = __builtin_amdgcn_mfma_f32_16x16x32_bf16(ah[mf], bh[nf], acc[mf][nf], 0, 0, 0);
                    acc[mf][nf] = __builtin_amdgcn_mfma_f32_16x16x32_bf16(ah[mf], bl[nf], acc[mf][nf], 0, 0, 0);
                    acc[mf][nf] = __builtin_amdgcn_mfma_f32_16x16x32_bf16(al[mf], bh[nf], acc[mf][nf], 0, 0, 0);
                }
        }
    }

    const int l4 = lane & 15, lr = lane >> 4;
    #pragma unroll
    for (int nf = 0; nf < 4; ++nf) {
        const int col = n0 + wn + nf * 16 + l4;
        if (col < Nout) {
            const float bv = bias[col];
            #pragma unroll
            for (int mf = 0; mf < 4; ++mf) {
                const int rowb = row0 + wm + mf * 16 + lr * 4;
                #pragma unroll
                for (int r = 0; r < 4; ++r)
                    out[(size_t)(rowb + r) * Nout + col] = acc[mf][nf][r] + bv;
            }
        }
    }
}

// ---------------------------------------------------------------------------
// Column sums of Wout (u[k]) + sum of bout (u[256]), f64 accum.
// ---------------------------------------------------------------------------
__global__ __launch_bounds__(256) void colsumW_k(const float* __restrict__ Wout,
                                                 const float* __restrict__ bout,
                                                 float* __restrict__ u)
{
    const int k = threadIdx.x;
    double s = 0.0;
    for (int col = 0; col < DOUTN; ++col) s += (double)Wout[(size_t)k * DOUTN + col];
    u[k] = (float)s;
    if (k == 0) {
        double b = 0.0;
        for (int col = 0; col < DOUTN; ++col) b += (double)bout[col];
        u[256] = (float)b;
    }
}

// ---------------------------------------------------------------------------
// Row-sum linearity check: rowsum(x) ?= s2.u + sum(bout). Trips *flag.
// ---------------------------------------------------------------------------
__global__ __launch_bounds__(256) void rowcheck_k(const float* __restrict__ x,
                                                  const float* __restrict__ h2,
                                                  const float* __restrict__ scf2,
                                                  const float* __restrict__ shf2,
                                                  const float* __restrict__ u,
                                                  int* __restrict__ flag)
{
    const int row = blockIdx.x;
    const int t = threadIdx.x;
    float rs = 0.f;
    for (int col = t; col < DOUTN; col += 256) rs += x[(size_t)row * DOUTN + col];
    const float s2v = fmaxf(fmaf(h2[(size_t)row * HDIM + t], scf2[t], shf2[t]), 0.f);
    float d = rs - s2v * u[t];
    #pragma unroll
    for (int o = 32; o > 0; o >>= 1) d += __shfl_down(d, o);
    __shared__ float red[4];
    if ((t & 63) == 0) red[t >> 6] = d;
    __syncthreads();
    if (t == 0) {
        const float tot = red[0] + red[1] + red[2] + red[3];
        if (fabsf(tot - u[256]) > 0.01f) *flag = 1;
    }
}

// ---------------------------------------------------------------------------
// Heads: tanh + hard gumbel one-hot in-place; flag small-gap groups.
// ---------------------------------------------------------------------------
__global__ __launch_bounds__(256) void heads_k(float* __restrict__ x,
                                               const float* __restrict__ gc,
                                               const float* __restrict__ gd,
                                               int* __restrict__ cnt,
                                               int* __restrict__ list)
{
    const int idx = blockIdx.x * 256 + threadIdx.x;
    const int row = idx / NGRP;
    const int g   = idx % NGRP;

    size_t base;
    const float* gum;
    if (g < 100) {
        base = (size_t)row * DOUTN + (size_t)g * 11 + 1;
        gum  = &gc[((size_t)row * 100 + g) * 10];
    } else {
        base = (size_t)row * DOUTN + 1100 + (size_t)(g - 100) * 10;
        gum  = &gd[((size_t)row * 100 + (g - 100)) * 10];
    }

    int am = 0;
    double best = -1e300, second = -1e300;
    #pragma unroll
    for (int m = 0; m < 10; ++m) {
        const double v = (double)x[base + m] + (double)gum[m];
        if (v > best) { second = best; best = v; am = m; }
        else if (v > second) second = v;
    }
    if (g < 100) {
        const size_t tc = base - 1;
        x[tc] = tanhf(x[tc]);
    }
    #pragma unroll
    for (int m = 0; m < 10; ++m) x[base + m] = (m == am) ? 1.0f : 0.0f;

    if (best - second < THETA) {
        const int p = atomicAdd(cnt, 1);
        if (p < FCAP) list[p] = (row << 8) | g;
    }
}

// ---------------------------------------------------------------------------
// f64 fallback: grid-stride over flagged (row,group); exact recompute.
// ---------------------------------------------------------------------------
__global__ __launch_bounds__(256) void fallback_k(
    const float* __restrict__ z,   const float* __restrict__ c,
    const float* __restrict__ W1,  const float* __restrict__ b1,
    const float* __restrict__ W2,  const float* __restrict__ b2,
    const float* __restrict__ Wout,const float* __restrict__ bout,
    const double* __restrict__ sc1,const double* __restrict__ sh1,
    const double* __restrict__ sc2,const double* __restrict__ sh2,
    const float* __restrict__ gc,  const float* __restrict__ gd,
    const int* __restrict__ cnt,   const int* __restrict__ list,
    float* __restrict__ x)
{
    int nf = *cnt;
    if (nf > FCAP) nf = FCAP;
    const int t = threadIdx.x;
    __shared__ double s1[HDIM], s2[HDIM], lg[16];

    for (int fi = blockIdx.x; fi < nf; fi += gridDim.x) {
        const int f   = list[fi];
        const int row = f >> 8, g = f & 255;

        double a = (double)b1[t];
        for (int k = 0; k < DIN; ++k) {
            const double iv = (k < 128) ? (double)z[(size_t)row * 128 + k]
                                        : (double)c[(size_t)row * 100 + k - 128];
            a = fma(iv, (double)W1[(size_t)k * HDIM + t], a);
        }
        const double v1 = fma(a, sc1[t], sh1[t]);
        s1[t] = v1 > 0.0 ? v1 : 0.0;
        __syncthreads();

        double a2 = (double)b2[t];
        for (int k = 0; k < HDIM; ++k)
            a2 = fma(s1[k], (double)W2[(size_t)k * HDIM + t], a2);
        for (int k = 0; k < DIN; ++k) {
            const double iv = (k < 128) ? (double)z[(size_t)row * 128 + k]
                                        : (double)c[(size_t)row * 100 + k - 128];
            a2 = fma(iv, (double)W2[(size_t)(HDIM + k) * HDIM + t], a2);
        }
        const double v2 = fma(a2, sc2[t], sh2[t]);
        s2[t] = v2 > 0.0 ? v2 : 0.0;
        __syncthreads();

        if (t < 10) {
            const int col = (g < 100) ? g * 11 + 1 + t : 1100 + (g - 100) * 10 + t;
            double d = (double)bout[col];
            for (int k = 0; k < HDIM; ++k)
                d = fma(s2[k], (double)Wout[(size_t)k * DOUTN + col], d);
            const double gv = (g < 100) ? (double)gc[((size_t)row * 100 + g) * 10 + t]
                                        : (double)gd[((size_t)row * 100 + (g - 100)) * 10 + t];
            lg[t] = d + gv;
        }
        __syncthreads();

        if (t == 0) {
            int am = 0;
            double best = lg[0];
            #pragma unroll
            for (int m = 1; m < 10; ++m)
                if (lg[m] > best) { best = lg[m]; am = m; }
            const size_t base = (g < 100) ? (size_t)row * DOUTN + (size_t)g * 11 + 1
                                          : (size_t)row * DOUTN + 1100 + (size_t)(g - 100) * 10;
            #pragma unroll
            for (int m = 0; m < 10; ++m) x[base + m] = (m == am) ? 1.0f : 0.0f;
        }
        __syncthreads();
    }
}

__global__ void zero_k(int* cnt, int* flag) {
    if (threadIdx.x == 0) { *cnt = 0; *flag = 0; }
}

// ---------------------------------------------------------------------------
extern "C" void kernel_launch(void* const* d_in, const int* in_sizes, int n_in,
                              void* d_out, int out_size, void* d_ws, size_t ws_size,
                              hipStream_t stream)
{
    (void)in_sizes; (void)n_in; (void)out_size; (void)ws_size;

    const float* z    = (const float*)d_in[0];
    const float* c    = (const float*)d_in[1];
    const float* W1   = (const float*)d_in[2];
    const float* b1   = (const float*)d_in[3];
    const float* g1   = (const float*)d_in[4];
    const float* be1  = (const float*)d_in[5];
    const float* W2   = (const float*)d_in[6];
    const float* b2   = (const float*)d_in[7];
    const float* g2   = (const float*)d_in[8];
    const float* be2  = (const float*)d_in[9];
    const float* Wout = (const float*)d_in[10];
    const float* bout = (const float*)d_in[11];
    const float* gc   = (const float*)d_in[12];
    const float* gd   = (const float*)d_in[13];
    float* out = (float*)d_out;

    // ---- workspace layout (f64 -> f32 -> u16 -> int) ----
    char* wp = (char*)d_ws;
    double* part = (double*)wp;            wp += 256 * 512 * 8;     // 1 MB
    double* sc1 = (double*)wp;             wp += 256 * 8;
    double* sh1 = (double*)wp;             wp += 256 * 8;
    double* sc2 = (double*)wp;             wp += 256 * 8;
    double* sh2 = (double*)wp;             wp += 256 * 8;
    float* scf1 = (float*)wp;              wp += 256 * 4;
    float* shf1 = (float*)wp;              wp += 256 * 4;
    float* scf2 = (float*)wp;              wp += 256 * 4;
    float* shf2 = (float*)wp;              wp += 256 * 4;
    float* u    = (float*)wp;              wp += 260 * 4;
    float* h1   = (float*)wp;              wp += (size_t)BATCH * 256 * 4;  // 16 MB
    float* h2   = (float*)wp;              wp += (size_t)BATCH * 256 * 4;  // 16 MB
    u16* A2hi   = (u16*)wp;                wp += (size_t)BATCH * 256 * 2;  // 8 MB
    u16* A2lo   = (u16*)wp;                wp += (size_t)BATCH * 256 * 2;  // 8 MB
    u16* Wothi  = (u16*)wp;                wp += 2176 * 256 * 2;
    u16* Wotlo  = (u16*)wp;                wp += 2176 * 256 * 2;
    int* cnt    = (int*)wp;                wp += 128;
    int* flag   = (int*)wp;                wp += 128;
    int* list   = (int*)wp;

    const dim3 blk(256);
    const dim3 gridH(2, BATCH / 128);    // (2, 128)
    const dim3 gridO(17, BATCH / 128);   // (17, 128)

    zero_k<<<dim3(1), dim3(64), 0, stream>>>(cnt, flag);
    colsumW_k<<<dim3(1), blk, 0, stream>>>(Wout, bout, u);

    // layers 1-2: R2-proven f32 path
    gemm_f32<0><<<gridH, blk, 0, stream>>>(z, c, nullptr, nullptr, nullptr, W1, b1, h1, nullptr);
    colsum2_k<<<dim3(256), blk, 0, stream>>>(h1, part);
    fin_k<<<dim3(1), blk, 0, stream>>>(part, g1, be1, sc1, sh1, scf1, shf1);

    gemm_f32<1><<<gridH, blk, 0, stream>>>(z, c, h1, scf1, shf1, W2, b2, h2, nullptr);
    colsum2_k<<<dim3(256), blk, 0, stream>>>(h2, part);
    fin_k<<<dim3(1), blk, 0, stream>>>(part, g2, be2, sc2, sh2, scf2, shf2);

    // mode-2 under test: MFMA bf16x3
    bnsplit_k<<<dim3(BATCH / 4), blk, 0, stream>>>(h2, scf2, shf2, A2hi, A2lo);
    splitW_k<<<dim3(9), blk, 0, stream>>>(Wout, 256, DOUTN, 256, 2176, Wothi, Wotlo);
    gemm_bf16x3<256><<<gridO, blk, 0, stream>>>(A2hi, A2lo, Wothi, Wotlo, bout, out, DOUTN);

    // net 1: linear row-sum check; net 2: gated f32 repair
    rowcheck_k<<<dim3(BATCH), blk, 0, stream>>>(out, h2, scf2, shf2, u, flag);
    gemm_f32<2><<<gridO, blk, 0, stream>>>(z, c, h2, scf2, shf2, Wout, bout, out, flag);

    // heads + f64 fallback net
    heads_k<<<dim3(BATCH * NGRP / 256), blk, 0, stream>>>(out, gc, gd, cnt, list);
    fallback_k<<<dim3(4096), blk, 0, stream>>>(z, c, W1, b1, W2, b2, Wout, bout,
                                               sc1, sh1, sc2, sh2, gc, gd, cnt, list, out);
}

// Round 6
// 664.198 us; speedup vs baseline: 1.2394x; 1.2394x over previous
//
#include <hip/hip_runtime.h>
#include <math.h>

#define BATCH 16384
#define HDIM  256
#define DIN   228    // 128 latent + 100 cond
#define DOUTN 2100
#define NGRP  200
#define THETA 2.5e-4 // top-2 gap below this -> f64 recompute (~2.8k flags, 20-sigma net)
#define FCAP  65536

typedef unsigned short u16;
typedef __attribute__((ext_vector_type(8))) short bf16x8;
typedef __attribute__((ext_vector_type(4))) float f32x4;
typedef __attribute__((ext_vector_type(8))) unsigned short u16x8;
typedef __attribute__((ext_vector_type(4))) unsigned short u16x4;

// RNE split: x = hi + lo (both bf16)
__device__ __forceinline__ void split_bf16(float x, u16& hi, u16& lo) {
    unsigned int u = __float_as_uint(x);
    unsigned int r = (u + 0x7fffu + ((u >> 16) & 1u)) >> 16;
    hi = (u16)r;
    const float hf = __uint_as_float(r << 16);
    const float l = x - hf;
    unsigned int u2 = __float_as_uint(l);
    unsigned int r2 = (u2 + 0x7fffu + ((u2 >> 16) & 1u)) >> 16;
    lo = (u16)r2;
}

// ---------------------------------------------------------------------------
// R2-PROVEN f32 tiled GEMM (gated). 128x128, KT=16, 256 thr, 8x8 microtile.
// MODE 0: h1 = i0 @ W1 + b1   MODE 1: h2 = [bnrelu(h1), i0] @ W2 + b2
// MODE 2: x = bnrelu(h2) @ Wout + bout   (repair path, gated on *gate != 0)
// ---------------------------------------------------------------------------
template <int MODE>
__global__ __launch_bounds__(256) void gemm_f32(
    const float* __restrict__ z,   const float* __restrict__ c,
    const float* __restrict__ hin,
    const float* __restrict__ scf, const float* __restrict__ shf,
    const float* __restrict__ W,   const float* __restrict__ bias,
    float* __restrict__ out,       const int* __restrict__ gate)
{
    if (gate && *gate == 0) return;

    constexpr int K  = (MODE == 0) ? DIN : (MODE == 1) ? (HDIM + DIN) : HDIM;
    constexpr int N  = (MODE == 2) ? DOUTN : HDIM;
    constexpr int KT = 16, BM = 128, BN = 128;

    __shared__ float Ash[KT][BM + 4];
    __shared__ float Bsh[KT][BN + 4];

    const int tid  = threadIdx.x;
    const int row0 = blockIdx.y * BM;
    const int n0   = blockIdx.x * BN;
    const int tx   = tid & 15, ty = tid >> 4;
    const int arow = tid >> 1, ahalf = (tid & 1) * 8;
    const int bkk  = tid >> 4, bc = (tid & 15) * 8;
    const bool nfast = (n0 + BN <= N);

    float acc[2][2][4][4] = {};

    for (int kt = 0; kt < K; kt += KT) {
        __syncthreads();
        #pragma unroll
        for (int q = 0; q < 8; ++q) {
            const int gk = kt + ahalf + q;
            float v = 0.f;
            if (MODE == 0) {
                if (gk < DIN)
                    v = (gk < 128) ? z[(size_t)(row0 + arow) * 128 + gk]
                                   : c[(size_t)(row0 + arow) * 100 + gk - 128];
            } else if (MODE == 1) {
                if (gk < HDIM) {
                    const float h = hin[(size_t)(row0 + arow) * HDIM + gk];
                    const float s = fmaf(h, scf[gk], shf[gk]);
                    v = s > 0.f ? s : 0.f;
                } else if (gk < HDIM + DIN) {
                    const int k2 = gk - HDIM;
                    v = (k2 < 128) ? z[(size_t)(row0 + arow) * 128 + k2]
                                   : c[(size_t)(row0 + arow) * 100 + k2 - 128];
                }
            } else {
                const float h = hin[(size_t)(row0 + arow) * HDIM + gk];
                const float s = fmaf(h, scf[gk], shf[gk]);
                v = s > 0.f ? s : 0.f;
            }
            Ash[ahalf + q][arow] = v;
        }
        {
            const int gk = kt + bkk;
            if (nfast && gk < K) {
                const float4 w0 = *reinterpret_cast<const float4*>(&W[(size_t)gk * N + n0 + bc]);
                const float4 w1 = *reinterpret_cast<const float4*>(&W[(size_t)gk * N + n0 + bc + 4]);
                *reinterpret_cast<float4*>(&Bsh[bkk][bc])     = w0;
                *reinterpret_cast<float4*>(&Bsh[bkk][bc + 4]) = w1;
            } else {
                #pragma unroll
                for (int q = 0; q < 8; ++q) {
                    const int gn = n0 + bc + q;
                    Bsh[bkk][bc + q] = (gk < K && gn < N) ? W[(size_t)gk * N + gn] : 0.f;
                }
            }
        }
        __syncthreads();
        #pragma unroll
        for (int kk = 0; kk < KT; ++kk) {
            float a[2][4], b[2][4];
            *reinterpret_cast<float4*>(a[0]) = *reinterpret_cast<const float4*>(&Ash[kk][ty * 4]);
            *reinterpret_cast<float4*>(a[1]) = *reinterpret_cast<const float4*>(&Ash[kk][64 + ty * 4]);
            *reinterpret_cast<float4*>(b[0]) = *reinterpret_cast<const float4*>(&Bsh[kk][tx * 4]);
            *reinterpret_cast<float4*>(b[1]) = *reinterpret_cast<const float4*>(&Bsh[kk][64 + tx * 4]);
            #pragma unroll
            for (int rb = 0; rb < 2; ++rb)
                #pragma unroll
                for (int cb = 0; cb < 2; ++cb)
                    #pragma unroll
                    for (int i = 0; i < 4; ++i)
                        #pragma unroll
                        for (int j = 0; j < 4; ++j)
                            acc[rb][cb][i][j] = fmaf(a[rb][i], b[cb][j], acc[rb][cb][i][j]);
        }
    }

    #pragma unroll
    for (int rb = 0; rb < 2; ++rb)
        #pragma unroll
        for (int i = 0; i < 4; ++i) {
            const size_t row = row0 + rb * 64 + ty * 4 + i;
            #pragma unroll
            for (int cb = 0; cb < 2; ++cb) {
                const int n = n0 + cb * 64 + tx * 4;
                if (nfast) {
                    float4 r;
                    r.x = acc[rb][cb][i][0] + bias[n + 0];
                    r.y = acc[rb][cb][i][1] + bias[n + 1];
                    r.z = acc[rb][cb][i][2] + bias[n + 2];
                    r.w = acc[rb][cb][i][3] + bias[n + 3];
                    *reinterpret_cast<float4*>(&out[row * N + n]) = r;
                } else {
                    #pragma unroll
                    for (int j = 0; j < 4; ++j)
                        if (n + j < N) out[row * N + n + j] = acc[rb][cb][i][j] + bias[n + j];
                }
            }
        }
}

// ---------------------------------------------------------------------------
// BN stats: fused column sum+sumsq, f64, 256 blocks x 64 rows.
// ---------------------------------------------------------------------------
__global__ __launch_bounds__(256) void colsum2_k(const float* __restrict__ h,
                                                 double* __restrict__ part)
{
    const int col = threadIdx.x;
    const size_t b0 = (size_t)blockIdx.x * 64;
    double s = 0.0, q = 0.0;
    for (int r = 0; r < 64; ++r) {
        const double v = (double)h[(b0 + r) * HDIM + col];
        s += v;
        q = fma(v, v, q);
    }
    part[(size_t)blockIdx.x * 512 + col]       = s;
    part[(size_t)blockIdx.x * 512 + 256 + col] = q;
}

__global__ __launch_bounds__(256) void fin_k(const double* __restrict__ part,
                                             const float* __restrict__ g,
                                             const float* __restrict__ be,
                                             double* __restrict__ sc64,
                                             double* __restrict__ sh64,
                                             float* __restrict__ scf,
                                             float* __restrict__ shf)
{
    const int col = threadIdx.x;
    double s = 0.0, q = 0.0;
    for (int i = 0; i < 256; ++i) {
        s += part[(size_t)i * 512 + col];
        q += part[(size_t)i * 512 + 256 + col];
    }
    const double mu    = s / (double)BATCH;
    const double var   = q / (double)BATCH - mu * mu;
    const double rs    = 1.0 / sqrt(var + 1e-5);
    const double scale = rs * (double)g[col];
    const double shift = (double)be[col] - mu * scale;
    sc64[col] = scale;  sh64[col] = shift;
    scf[col]  = (float)scale;  shf[col] = (float)shift;
}

// ---------------------------------------------------------------------------
// BN+relu+split h2 -> A2 planes [B][256] bf16 hi/lo.
// ---------------------------------------------------------------------------
__global__ __launch_bounds__(256) void bnsplit_k(const float* __restrict__ h,
                                                 const float* __restrict__ scf,
                                                 const float* __restrict__ shf,
                                                 u16* __restrict__ hi, u16* __restrict__ lo)
{
    const int t = blockIdx.x * 256 + threadIdx.x;   // BATCH*64
    const int row = t >> 6, c4 = (t & 63) * 4;
    const float4 v = *(const float4*)&h[(size_t)row * 256 + c4];
    const float vv[4] = {v.x, v.y, v.z, v.w};
    u16x4 H, L;
    #pragma unroll
    for (int j = 0; j < 4; ++j) {
        float s = fmaf(vv[j], scf[c4 + j], shf[c4 + j]);
        s = fmaxf(s, 0.f);
        u16 hh, ll; split_bf16(s, hh, ll);
        H[j] = hh; L[j] = ll;
    }
    *(u16x4*)&hi[(size_t)row * 256 + c4] = H;
    *(u16x4*)&lo[(size_t)row * 256 + c4] = L;
}

// ---------------------------------------------------------------------------
// Transpose + split Wout: [256][2100] f32 -> planes [2176][256] bf16.
// ---------------------------------------------------------------------------
__global__ __launch_bounds__(256) void splitW_k(const float* __restrict__ W,
                                                int K0, int N0, int Kpad, int Npad,
                                                u16* __restrict__ Whi, u16* __restrict__ Wlo)
{
    const int n = blockIdx.x * 256 + threadIdx.x;
    if (n >= Npad) return;
    for (int kb = 0; kb < Kpad; kb += 8) {
        u16x8 H, L;
        #pragma unroll
        for (int j = 0; j < 8; ++j) {
            const int k = kb + j;
            const float x = (k < K0 && n < N0) ? W[(size_t)k * N0 + n] : 0.f;
            u16 h, l; split_bf16(x, h, l);
            H[j] = h; L[j] = l;
        }
        *(u16x8*)&Whi[(size_t)n * Kpad + kb] = H;
        *(u16x8*)&Wlo[(size_t)n * Kpad + kb] = L;
    }
}

// ---------------------------------------------------------------------------
// bf16x3 MFMA GEMM (PROVEN R5): A [M][256], B [2176][256], 128x128 tile.
// Reg-staged LDS, chunk-XOR swizzle identical on write and read.
// ---------------------------------------------------------------------------
template <int K>
__global__ __launch_bounds__(256) void gemm_bf16x3(
    const u16* __restrict__ Ahi, const u16* __restrict__ Alo,
    const u16* __restrict__ Bhi, const u16* __restrict__ Blo,
    const float* __restrict__ bias, float* __restrict__ out, int Nout)
{
    __shared__ __align__(16) u16 lds[4 * 128 * 64];
    u16* Ah = lds;
    u16* Al = lds + 8192;
    u16* Bh = lds + 16384;
    u16* Bl = lds + 24576;

    const int tid  = threadIdx.x;
    const int lane = tid & 63;
    const int w    = tid >> 6;
    const int wm   = (w >> 1) * 64, wn = (w & 1) * 64;
    const int row0 = blockIdx.y * 128, n0 = blockIdx.x * 128;

    const u16* gAh = Ahi + (size_t)row0 * K;
    const u16* gAl = Alo + (size_t)row0 * K;
    const u16* gBh = Bhi + (size_t)n0 * K;
    const u16* gBl = Blo + (size_t)n0 * K;

    f32x4 acc[4][4] = {};

    for (int kc = 0; kc < K; kc += 64) {
        __syncthreads();
        #pragma unroll
        for (int q = 0; q < 4; ++q) {
            const int cidx = q * 256 + tid;
            const int r = cidx >> 3, s = cidx & 7;
            const size_t go = (size_t)r * K + kc + s * 8;
            const int lo = r * 64 + ((s ^ (r & 7)) * 8);
            const u16x8 va = *(const u16x8*)(gAh + go);
            const u16x8 vb = *(const u16x8*)(gAl + go);
            const u16x8 vc = *(const u16x8*)(gBh + go);
            const u16x8 vd = *(const u16x8*)(gBl + go);
            *(u16x8*)(Ah + lo) = va;
            *(u16x8*)(Al + lo) = vb;
            *(u16x8*)(Bh + lo) = vc;
            *(u16x8*)(Bl + lo) = vd;
        }
        __syncthreads();

        #pragma unroll
        for (int ks = 0; ks < 2; ++ks) {
            bf16x8 ah[4], al[4], bh[4], bl[4];
            const int o = (ks * 4 + (lane >> 4)) * 8;
            #pragma unroll
            for (int mf = 0; mf < 4; ++mf) {
                const int r = wm + mf * 16 + (lane & 15);
                const int off = r * 64 + (o ^ ((r & 7) * 8));
                ah[mf] = *(const bf16x8*)(Ah + off);
                al[mf] = *(const bf16x8*)(Al + off);
            }
            #pragma unroll
            for (int nf = 0; nf < 4; ++nf) {
                const int r = wn + nf * 16 + (lane & 15);
                const int off = r * 64 + (o ^ ((r & 7) * 8));
                bh[nf] = *(const bf16x8*)(Bh + off);
                bl[nf] = *(const bf16x8*)(Bl + off);
            }
            #pragma unroll
            for (int mf = 0; mf < 4; ++mf)
                #pragma unroll
                for (int nf = 0; nf < 4; ++nf) {
                    acc[mf][nf] = __builtin_amdgcn_mfma_f32_16x16x32_bf16(ah[mf], bh[nf], acc[mf][nf], 0, 0, 0);
                    acc[mf][nf] = __builtin_amdgcn_mfma_f32_16x16x32_bf16(ah[mf], bl[nf], acc[mf][nf], 0, 0, 0);
                    acc[mf][nf] = __builtin_amdgcn_mfma_f32_16x16x32_bf16(al[mf], bh[nf], acc[mf][nf], 0, 0, 0);
                }
        }
    }

    const int l4 = lane & 15, lr = lane >> 4;
    #pragma unroll
    for (int nf = 0; nf < 4; ++nf) {
        const int col = n0 + wn + nf * 16 + l4;
        if (col < Nout) {
            const float bv = bias[col];
            #pragma unroll
            for (int mf = 0; mf < 4; ++mf) {
                const int rowb = row0 + wm + mf * 16 + lr * 4;
                #pragma unroll
                for (int r = 0; r < 4; ++r)
                    out[(size_t)(rowb + r) * Nout + col] = acc[mf][nf][r] + bv;
            }
        }
    }
}

// ---------------------------------------------------------------------------
// Column sums of Wout (u[k]) + sum of bout (u[256]), f64 accum.
// ---------------------------------------------------------------------------
__global__ __launch_bounds__(256) void colsumW_k(const float* __restrict__ Wout,
                                                 const float* __restrict__ bout,
                                                 float* __restrict__ u)
{
    const int k = threadIdx.x;
    double s = 0.0;
    for (int col = 0; col < DOUTN; ++col) s += (double)Wout[(size_t)k * DOUTN + col];
    u[k] = (float)s;
    if (k == 0) {
        double b = 0.0;
        for (int col = 0; col < DOUTN; ++col) b += (double)bout[col];
        u[256] = (float)b;
    }
}

// ---------------------------------------------------------------------------
// Row-sum linearity check: rowsum(x) ?= s2.u + sum(bout). Trips *flag.
// ---------------------------------------------------------------------------
__global__ __launch_bounds__(256) void rowcheck_k(const float* __restrict__ x,
                                                  const float* __restrict__ h2,
                                                  const float* __restrict__ scf2,
                                                  const float* __restrict__ shf2,
                                                  const float* __restrict__ u,
                                                  int* __restrict__ flag)
{
    const int row = blockIdx.x;
    const int t = threadIdx.x;
    float rs = 0.f;
    for (int col = t; col < DOUTN; col += 256) rs += x[(size_t)row * DOUTN + col];
    const float s2v = fmaxf(fmaf(h2[(size_t)row * HDIM + t], scf2[t], shf2[t]), 0.f);
    float d = rs - s2v * u[t];
    #pragma unroll
    for (int o = 32; o > 0; o >>= 1) d += __shfl_down(d, o);
    __shared__ float red[4];
    if ((t & 63) == 0) red[t >> 6] = d;
    __syncthreads();
    if (t == 0) {
        const float tot = red[0] + red[1] + red[2] + red[3];
        if (fabsf(tot - u[256]) > 0.01f) *flag = 1;
    }
}

// ---------------------------------------------------------------------------
// Heads: tanh + hard gumbel one-hot in-place; flag small-gap groups.
// ---------------------------------------------------------------------------
__global__ __launch_bounds__(256) void heads_k(float* __restrict__ x,
                                               const float* __restrict__ gc,
                                               const float* __restrict__ gd,
                                               int* __restrict__ cnt,
                                               int* __restrict__ list)
{
    const int idx = blockIdx.x * 256 + threadIdx.x;
    const int row = idx / NGRP;
    const int g   = idx % NGRP;

    size_t base;
    const float* gum;
    if (g < 100) {
        base = (size_t)row * DOUTN + (size_t)g * 11 + 1;
        gum  = &gc[((size_t)row * 100 + g) * 10];
    } else {
        base = (size_t)row * DOUTN + 1100 + (size_t)(g - 100) * 10;
        gum  = &gd[((size_t)row * 100 + (g - 100)) * 10];
    }

    int am = 0;
    double best = -1e300, second = -1e300;
    #pragma unroll
    for (int m = 0; m < 10; ++m) {
        const double v = (double)x[base + m] + (double)gum[m];
        if (v > best) { second = best; best = v; am = m; }
        else if (v > second) second = v;
    }
    if (g < 100) {
        const size_t tc = base - 1;
        x[tc] = tanhf(x[tc]);
    }
    #pragma unroll
    for (int m = 0; m < 10; ++m) x[base + m] = (m == am) ? 1.0f : 0.0f;

    if (best - second < THETA) {
        const int p = atomicAdd(cnt, 1);
        if (p < FCAP) list[p] = (row << 8) | g;
    }
}

// ---------------------------------------------------------------------------
// f64 fallback: grid-stride over flagged (row,group); exact recompute.
// ---------------------------------------------------------------------------
__global__ __launch_bounds__(256) void fallback_k(
    const float* __restrict__ z,   const float* __restrict__ c,
    const float* __restrict__ W1,  const float* __restrict__ b1,
    const float* __restrict__ W2,  const float* __restrict__ b2,
    const float* __restrict__ Wout,const float* __restrict__ bout,
    const double* __restrict__ sc1,const double* __restrict__ sh1,
    const double* __restrict__ sc2,const double* __restrict__ sh2,
    const float* __restrict__ gc,  const float* __restrict__ gd,
    const int* __restrict__ cnt,   const int* __restrict__ list,
    float* __restrict__ x)
{
    int nf = *cnt;
    if (nf > FCAP) nf = FCAP;
    const int t = threadIdx.x;
    __shared__ double s1[HDIM], s2[HDIM], lg[16];

    for (int fi = blockIdx.x; fi < nf; fi += gridDim.x) {
        const int f   = list[fi];
        const int row = f >> 8, g = f & 255;

        double a = (double)b1[t];
        for (int k = 0; k < DIN; ++k) {
            const double iv = (k < 128) ? (double)z[(size_t)row * 128 + k]
                                        : (double)c[(size_t)row * 100 + k - 128];
            a = fma(iv, (double)W1[(size_t)k * HDIM + t], a);
        }
        const double v1 = fma(a, sc1[t], sh1[t]);
        s1[t] = v1 > 0.0 ? v1 : 0.0;
        __syncthreads();

        double a2 = (double)b2[t];
        for (int k = 0; k < HDIM; ++k)
            a2 = fma(s1[k], (double)W2[(size_t)k * HDIM + t], a2);
        for (int k = 0; k < DIN; ++k) {
            const double iv = (k < 128) ? (double)z[(size_t)row * 128 + k]
                                        : (double)c[(size_t)row * 100 + k - 128];
            a2 = fma(iv, (double)W2[(size_t)(HDIM + k) * HDIM + t], a2);
        }
        const double v2 = fma(a2, sc2[t], sh2[t]);
        s2[t] = v2 > 0.0 ? v2 : 0.0;
        __syncthreads();

        if (t < 10) {
            const int col = (g < 100) ? g * 11 + 1 + t : 1100 + (g - 100) * 10 + t;
            double d = (double)bout[col];
            for (int k = 0; k < HDIM; ++k)
                d = fma(s2[k], (double)Wout[(size_t)k * DOUTN + col], d);
            const double gv = (g < 100) ? (double)gc[((size_t)row * 100 + g) * 10 + t]
                                        : (double)gd[((size_t)row * 100 + (g - 100)) * 10 + t];
            lg[t] = d + gv;
        }
        __syncthreads();

        if (t == 0) {
            int am = 0;
            double best = lg[0];
            #pragma unroll
            for (int m = 1; m < 10; ++m)
                if (lg[m] > best) { best = lg[m]; am = m; }
            const size_t base = (g < 100) ? (size_t)row * DOUTN + (size_t)g * 11 + 1
                                          : (size_t)row * DOUTN + 1100 + (size_t)(g - 100) * 10;
            #pragma unroll
            for (int m = 0; m < 10; ++m) x[base + m] = (m == am) ? 1.0f : 0.0f;
        }
        __syncthreads();
    }
}

__global__ void zero_k(int* cnt, int* flag) {
    if (threadIdx.x == 0) { *cnt = 0; *flag = 0; }
}

// ---------------------------------------------------------------------------
extern "C" void kernel_launch(void* const* d_in, const int* in_sizes, int n_in,
                              void* d_out, int out_size, void* d_ws, size_t ws_size,
                              hipStream_t stream)
{
    (void)in_sizes; (void)n_in; (void)out_size; (void)ws_size;

    const float* z    = (const float*)d_in[0];
    const float* c    = (const float*)d_in[1];
    const float* W1   = (const float*)d_in[2];
    const float* b1   = (const float*)d_in[3];
    const float* g1   = (const float*)d_in[4];
    const float* be1  = (const float*)d_in[5];
    const float* W2   = (const float*)d_in[6];
    const float* b2   = (const float*)d_in[7];
    const float* g2   = (const float*)d_in[8];
    const float* be2  = (const float*)d_in[9];
    const float* Wout = (const float*)d_in[10];
    const float* bout = (const float*)d_in[11];
    const float* gc   = (const float*)d_in[12];
    const float* gd   = (const float*)d_in[13];
    float* out = (float*)d_out;

    // ---- workspace layout (f64 -> f32 -> u16 -> int) ----
    char* wp = (char*)d_ws;
    double* part = (double*)wp;            wp += 256 * 512 * 8;     // 1 MB
    double* sc1 = (double*)wp;             wp += 256 * 8;
    double* sh1 = (double*)wp;             wp += 256 * 8;
    double* sc2 = (double*)wp;             wp += 256 * 8;
    double* sh2 = (double*)wp;             wp += 256 * 8;
    float* scf1 = (float*)wp;              wp += 256 * 4;
    float* shf1 = (float*)wp;              wp += 256 * 4;
    float* scf2 = (float*)wp;              wp += 256 * 4;
    float* shf2 = (float*)wp;              wp += 256 * 4;
    float* u    = (float*)wp;              wp += 260 * 4;
    float* h1   = (float*)wp;              wp += (size_t)BATCH * 256 * 4;  // 16 MB
    float* h2   = (float*)wp;              wp += (size_t)BATCH * 256 * 4;  // 16 MB
    u16* A2hi   = (u16*)wp;                wp += (size_t)BATCH * 256 * 2;  // 8 MB
    u16* A2lo   = (u16*)wp;                wp += (size_t)BATCH * 256 * 2;  // 8 MB
    u16* Wothi  = (u16*)wp;                wp += 2176 * 256 * 2;
    u16* Wotlo  = (u16*)wp;                wp += 2176 * 256 * 2;
    int* cnt    = (int*)wp;                wp += 128;
    int* flag   = (int*)wp;                wp += 128;
    int* list   = (int*)wp;

    const dim3 blk(256);
    const dim3 gridH(2, BATCH / 128);    // (2, 128)
    const dim3 gridO(17, BATCH / 128);   // (17, 128)

    zero_k<<<dim3(1), dim3(64), 0, stream>>>(cnt, flag);
    colsumW_k<<<dim3(1), blk, 0, stream>>>(Wout, bout, u);

    // layers 1-2: f32 path (stat-feeding layers stay f32: stat err ~1e-8,
    // keeps the f64-fallback-vs-reference flip risk at the proven level)
    gemm_f32<0><<<gridH, blk, 0, stream>>>(z, c, nullptr, nullptr, nullptr, W1, b1, h1, nullptr);
    colsum2_k<<<dim3(256), blk, 0, stream>>>(h1, part);
    fin_k<<<dim3(1), blk, 0, stream>>>(part, g1, be1, sc1, sh1, scf1, shf1);

    gemm_f32<1><<<gridH, blk, 0, stream>>>(z, c, h1, scf1, shf1, W2, b2, h2, nullptr);
    colsum2_k<<<dim3(256), blk, 0, stream>>>(h2, part);
    fin_k<<<dim3(1), blk, 0, stream>>>(part, g2, be2, sc2, sh2, scf2, shf2);

    // mode-2: MFMA bf16x3 (proven R5)
    bnsplit_k<<<dim3(BATCH / 4), blk, 0, stream>>>(h2, scf2, shf2, A2hi, A2lo);
    splitW_k<<<dim3(9), blk, 0, stream>>>(Wout, 256, DOUTN, 256, 2176, Wothi, Wotlo);
    gemm_bf16x3<256><<<gridO, blk, 0, stream>>>(A2hi, A2lo, Wothi, Wotlo, bout, out, DOUTN);

    // safety net: linearity check + gated f32 repair
    rowcheck_k<<<dim3(BATCH), blk, 0, stream>>>(out, h2, scf2, shf2, u, flag);
    gemm_f32<2><<<gridO, blk, 0, stream>>>(z, c, h2, scf2, shf2, Wout, bout, out, flag);

    // heads + f64 fallback net
    heads_k<<<dim3(BATCH * NGRP / 256), blk, 0, stream>>>(out, gc, gd, cnt, list);
    fallback_k<<<dim3(4096), blk, 0, stream>>>(z, c, W1, b1, W2, b2, Wout, bout,
                                               sc1, sh1, sc2, sh2, gc, gd, cnt, list, out);
}

// Round 7
// 442.866 us; speedup vs baseline: 1.8589x; 1.4998x over previous
//
#include <hip/hip_runtime.h>
#include <math.h>

#define BATCH 16384
#define HDIM  256
#define DIN   228    // 128 latent + 100 cond
#define DOUTN 2100
#define NGRP  200
#define THETA 2.5e-4 // top-2 gap below this -> f64 recompute (~2.8k flags, 20-sigma net)
#define FCAP  65536

typedef unsigned short u16;
typedef __attribute__((ext_vector_type(8))) short bf16x8;
typedef __attribute__((ext_vector_type(4))) float f32x4;
typedef __attribute__((ext_vector_type(8))) unsigned short u16x8;
typedef __attribute__((ext_vector_type(4))) unsigned short u16x4;

// RNE split: x = hi + lo (both bf16)
__device__ __forceinline__ void split_bf16(float x, u16& hi, u16& lo) {
    unsigned int u = __float_as_uint(x);
    unsigned int r = (u + 0x7fffu + ((u >> 16) & 1u)) >> 16;
    hi = (u16)r;
    const float hf = __uint_as_float(r << 16);
    const float l = x - hf;
    unsigned int u2 = __float_as_uint(l);
    unsigned int r2 = (u2 + 0x7fffu + ((u2 >> 16) & 1u)) >> 16;
    lo = (u16)r2;
}

// ---------------------------------------------------------------------------
// f32 tiled GEMM (layers 1-2; stat-feeding layers stay f32 for precision).
// 128x128, KT=16, 256 thr, 8x8 microtile.
// MODE 0: h1 = i0 @ W1 + b1   MODE 1: h2 = [bnrelu(h1), i0] @ W2 + b2
// ---------------------------------------------------------------------------
template <int MODE>
__global__ __launch_bounds__(256) void gemm_f32(
    const float* __restrict__ z,   const float* __restrict__ c,
    const float* __restrict__ hin,
    const float* __restrict__ scf, const float* __restrict__ shf,
    const float* __restrict__ W,   const float* __restrict__ bias,
    float* __restrict__ out)
{
    constexpr int K  = (MODE == 0) ? DIN : (HDIM + DIN);
    constexpr int N  = HDIM;
    constexpr int KT = 16, BM = 128, BN = 128;

    __shared__ float Ash[KT][BM + 4];
    __shared__ float Bsh[KT][BN + 4];

    const int tid  = threadIdx.x;
    const int row0 = blockIdx.y * BM;
    const int n0   = blockIdx.x * BN;
    const int tx   = tid & 15, ty = tid >> 4;
    const int arow = tid >> 1, ahalf = (tid & 1) * 8;
    const int bkk  = tid >> 4, bc = (tid & 15) * 8;

    float acc[2][2][4][4] = {};

    for (int kt = 0; kt < K; kt += KT) {
        __syncthreads();
        #pragma unroll
        for (int q = 0; q < 8; ++q) {
            const int gk = kt + ahalf + q;
            float v = 0.f;
            if (MODE == 0) {
                if (gk < DIN)
                    v = (gk < 128) ? z[(size_t)(row0 + arow) * 128 + gk]
                                   : c[(size_t)(row0 + arow) * 100 + gk - 128];
            } else {
                if (gk < HDIM) {
                    const float h = hin[(size_t)(row0 + arow) * HDIM + gk];
                    const float s = fmaf(h, scf[gk], shf[gk]);
                    v = s > 0.f ? s : 0.f;
                } else if (gk < HDIM + DIN) {
                    const int k2 = gk - HDIM;
                    v = (k2 < 128) ? z[(size_t)(row0 + arow) * 128 + k2]
                                   : c[(size_t)(row0 + arow) * 100 + k2 - 128];
                }
            }
            Ash[ahalf + q][arow] = v;
        }
        {
            const int gk = kt + bkk;
            if (gk < K) {
                const float4 w0 = *reinterpret_cast<const float4*>(&W[(size_t)gk * N + n0 + bc]);
                const float4 w1 = *reinterpret_cast<const float4*>(&W[(size_t)gk * N + n0 + bc + 4]);
                *reinterpret_cast<float4*>(&Bsh[bkk][bc])     = w0;
                *reinterpret_cast<float4*>(&Bsh[bkk][bc + 4]) = w1;
            } else {
                #pragma unroll
                for (int q = 0; q < 8; ++q) Bsh[bkk][bc + q] = 0.f;
            }
        }
        __syncthreads();
        #pragma unroll
        for (int kk = 0; kk < KT; ++kk) {
            float a[2][4], b[2][4];
            *reinterpret_cast<float4*>(a[0]) = *reinterpret_cast<const float4*>(&Ash[kk][ty * 4]);
            *reinterpret_cast<float4*>(a[1]) = *reinterpret_cast<const float4*>(&Ash[kk][64 + ty * 4]);
            *reinterpret_cast<float4*>(b[0]) = *reinterpret_cast<const float4*>(&Bsh[kk][tx * 4]);
            *reinterpret_cast<float4*>(b[1]) = *reinterpret_cast<const float4*>(&Bsh[kk][64 + tx * 4]);
            #pragma unroll
            for (int rb = 0; rb < 2; ++rb)
                #pragma unroll
                for (int cb = 0; cb < 2; ++cb)
                    #pragma unroll
                    for (int i = 0; i < 4; ++i)
                        #pragma unroll
                        for (int j = 0; j < 4; ++j)
                            acc[rb][cb][i][j] = fmaf(a[rb][i], b[cb][j], acc[rb][cb][i][j]);
        }
    }

    #pragma unroll
    for (int rb = 0; rb < 2; ++rb)
        #pragma unroll
        for (int i = 0; i < 4; ++i) {
            const size_t row = row0 + rb * 64 + ty * 4 + i;
            #pragma unroll
            for (int cb = 0; cb < 2; ++cb) {
                const int n = n0 + cb * 64 + tx * 4;
                float4 r;
                r.x = acc[rb][cb][i][0] + bias[n + 0];
                r.y = acc[rb][cb][i][1] + bias[n + 1];
                r.z = acc[rb][cb][i][2] + bias[n + 2];
                r.w = acc[rb][cb][i][3] + bias[n + 3];
                *reinterpret_cast<float4*>(&out[row * N + n]) = r;
            }
        }
}

// ---------------------------------------------------------------------------
// BN stats: fused column sum+sumsq, f64, 256 blocks x 64 rows.
// ---------------------------------------------------------------------------
__global__ __launch_bounds__(256) void colsum2_k(const float* __restrict__ h,
                                                 double* __restrict__ part)
{
    const int col = threadIdx.x;
    const size_t b0 = (size_t)blockIdx.x * 64;
    double s = 0.0, q = 0.0;
    for (int r = 0; r < 64; ++r) {
        const double v = (double)h[(b0 + r) * HDIM + col];
        s += v;
        q = fma(v, v, q);
    }
    part[(size_t)blockIdx.x * 512 + col]       = s;
    part[(size_t)blockIdx.x * 512 + 256 + col] = q;
}

__global__ __launch_bounds__(256) void fin_k(const double* __restrict__ part,
                                             const float* __restrict__ g,
                                             const float* __restrict__ be,
                                             double* __restrict__ sc64,
                                             double* __restrict__ sh64,
                                             float* __restrict__ scf,
                                             float* __restrict__ shf)
{
    const int col = threadIdx.x;
    double s = 0.0, q = 0.0;
    for (int i = 0; i < 256; ++i) {
        s += part[(size_t)i * 512 + col];
        q += part[(size_t)i * 512 + 256 + col];
    }
    const double mu    = s / (double)BATCH;
    const double var   = q / (double)BATCH - mu * mu;
    const double rs    = 1.0 / sqrt(var + 1e-5);
    const double scale = rs * (double)g[col];
    const double shift = (double)be[col] - mu * scale;
    sc64[col] = scale;  sh64[col] = shift;
    scf[col]  = (float)scale;  shf[col] = (float)shift;
}

// ---------------------------------------------------------------------------
// BN+relu+split h2 -> A2 planes [B][256] bf16 hi/lo.
// ---------------------------------------------------------------------------
__global__ __launch_bounds__(256) void bnsplit_k(const float* __restrict__ h,
                                                 const float* __restrict__ scf,
                                                 const float* __restrict__ shf,
                                                 u16* __restrict__ hi, u16* __restrict__ lo)
{
    const int t = blockIdx.x * 256 + threadIdx.x;   // BATCH*64
    const int row = t >> 6, c4 = (t & 63) * 4;
    const float4 v = *(const float4*)&h[(size_t)row * 256 + c4];
    const float vv[4] = {v.x, v.y, v.z, v.w};
    u16x4 H, L;
    #pragma unroll
    for (int j = 0; j < 4; ++j) {
        float s = fmaf(vv[j], scf[c4 + j], shf[c4 + j]);
        s = fmaxf(s, 0.f);
        u16 hh, ll; split_bf16(s, hh, ll);
        H[j] = hh; L[j] = ll;
    }
    *(u16x4*)&hi[(size_t)row * 256 + c4] = H;
    *(u16x4*)&lo[(size_t)row * 256 + c4] = L;
}

// ---------------------------------------------------------------------------
// Transpose + split Wout: [256][2100] f32 -> planes [2176][256] bf16.
// ---------------------------------------------------------------------------
__global__ __launch_bounds__(256) void splitW_k(const float* __restrict__ W,
                                                int K0, int N0, int Kpad, int Npad,
                                                u16* __restrict__ Whi, u16* __restrict__ Wlo)
{
    const int n = blockIdx.x * 256 + threadIdx.x;
    if (n >= Npad) return;
    for (int kb = 0; kb < Kpad; kb += 8) {
        u16x8 H, L;
        #pragma unroll
        for (int j = 0; j < 8; ++j) {
            const int k = kb + j;
            const float x = (k < K0 && n < N0) ? W[(size_t)k * N0 + n] : 0.f;
            u16 h, l; split_bf16(x, h, l);
            H[j] = h; L[j] = l;
        }
        *(u16x8*)&Whi[(size_t)n * Kpad + kb] = H;
        *(u16x8*)&Wlo[(size_t)n * Kpad + kb] = L;
    }
}

// ---------------------------------------------------------------------------
// bf16x3 MFMA GEMM (PROVEN R5/R6): A [M][256], B [2176][256], 128x128 tile.
// Reg-staged LDS, chunk-XOR swizzle identical on write and read.
// ---------------------------------------------------------------------------
template <int K>
__global__ __launch_bounds__(256) void gemm_bf16x3(
    const u16* __restrict__ Ahi, const u16* __restrict__ Alo,
    const u16* __restrict__ Bhi, const u16* __restrict__ Blo,
    const float* __restrict__ bias, float* __restrict__ out, int Nout)
{
    __shared__ __align__(16) u16 lds[4 * 128 * 64];
    u16* Ah = lds;
    u16* Al = lds + 8192;
    u16* Bh = lds + 16384;
    u16* Bl = lds + 24576;

    const int tid  = threadIdx.x;
    const int lane = tid & 63;
    const int w    = tid >> 6;
    const int wm   = (w >> 1) * 64, wn = (w & 1) * 64;
    const int row0 = blockIdx.y * 128, n0 = blockIdx.x * 128;

    const u16* gAh = Ahi + (size_t)row0 * K;
    const u16* gAl = Alo + (size_t)row0 * K;
    const u16* gBh = Bhi + (size_t)n0 * K;
    const u16* gBl = Blo + (size_t)n0 * K;

    f32x4 acc[4][4] = {};

    for (int kc = 0; kc < K; kc += 64) {
        __syncthreads();
        #pragma unroll
        for (int q = 0; q < 4; ++q) {
            const int cidx = q * 256 + tid;
            const int r = cidx >> 3, s = cidx & 7;
            const size_t go = (size_t)r * K + kc + s * 8;
            const int lo = r * 64 + ((s ^ (r & 7)) * 8);
            const u16x8 va = *(const u16x8*)(gAh + go);
            const u16x8 vb = *(const u16x8*)(gAl + go);
            const u16x8 vc = *(const u16x8*)(gBh + go);
            const u16x8 vd = *(const u16x8*)(gBl + go);
            *(u16x8*)(Ah + lo) = va;
            *(u16x8*)(Al + lo) = vb;
            *(u16x8*)(Bh + lo) = vc;
            *(u16x8*)(Bl + lo) = vd;
        }
        __syncthreads();

        #pragma unroll
        for (int ks = 0; ks < 2; ++ks) {
            bf16x8 ah[4], al[4], bh[4], bl[4];
            const int o = (ks * 4 + (lane >> 4)) * 8;
            #pragma unroll
            for (int mf = 0; mf < 4; ++mf) {
                const int r = wm + mf * 16 + (lane & 15);
                const int off = r * 64 + (o ^ ((r & 7) * 8));
                ah[mf] = *(const bf16x8*)(Ah + off);
                al[mf] = *(const bf16x8*)(Al + off);
            }
            #pragma unroll
            for (int nf = 0; nf < 4; ++nf) {
                const int r = wn + nf * 16 + (lane & 15);
                const int off = r * 64 + (o ^ ((r & 7) * 8));
                bh[nf] = *(const bf16x8*)(Bh + off);
                bl[nf] = *(const bf16x8*)(Bl + off);
            }
            #pragma unroll
            for (int mf = 0; mf < 4; ++mf)
                #pragma unroll
                for (int nf = 0; nf < 4; ++nf) {
                    acc[mf][nf] = __builtin_amdgcn_mfma_f32_16x16x32_bf16(ah[mf], bh[nf], acc[mf][nf], 0, 0, 0);
                    acc[mf][nf] = __builtin_amdgcn_mfma_f32_16x16x32_bf16(ah[mf], bl[nf], acc[mf][nf], 0, 0, 0);
                    acc[mf][nf] = __builtin_amdgcn_mfma_f32_16x16x32_bf16(al[mf], bh[nf], acc[mf][nf], 0, 0, 0);
                }
        }
    }

    const int l4 = lane & 15, lr = lane >> 4;
    #pragma unroll
    for (int nf = 0; nf < 4; ++nf) {
        const int col = n0 + wn + nf * 16 + l4;
        if (col < Nout) {
            const float bv = bias[col];
            #pragma unroll
            for (int mf = 0; mf < 4; ++mf) {
                const int rowb = row0 + wm + mf * 16 + lr * 4;
                #pragma unroll
                for (int r = 0; r < 4; ++r)
                    out[(size_t)(rowb + r) * Nout + col] = acc[mf][nf][r] + bv;
            }
        }
    }
}

// ---------------------------------------------------------------------------
// LDS-staged heads: one block per row. Coalesced float4 load of the row's
// x / gc / gd into LDS; 200 threads process one group each (f64 argmax,
// theta-flagging); coalesced float4 store back. Row strides are 16B-aligned:
// 2100*4=8400, 1000*4=4000.
// ---------------------------------------------------------------------------
__global__ __launch_bounds__(256) void heads2_k(float* __restrict__ x,
                                                const float* __restrict__ gc,
                                                const float* __restrict__ gd,
                                                int* __restrict__ cnt,
                                                int* __restrict__ list)
{
    __shared__ __align__(16) float xr[DOUTN];
    __shared__ __align__(16) float gr[2000];

    const int row = blockIdx.x;
    const int t   = threadIdx.x;

    const float4* gx = (const float4*)(x + (size_t)row * DOUTN);
    const float4* ggc = (const float4*)(gc + (size_t)row * 1000);
    const float4* ggd = (const float4*)(gd + (size_t)row * 1000);
    #pragma unroll 3
    for (int i = t; i < 525; i += 256) ((float4*)xr)[i] = gx[i];
    for (int i = t; i < 250; i += 256) ((float4*)gr)[i] = ggc[i];
    for (int i = t; i < 250; i += 256) ((float4*)(gr + 1000))[i] = ggd[i];
    __syncthreads();

    if (t < NGRP) {
        const int g = t;
        int base;
        const float* gum;
        if (g < 100) { base = g * 11 + 1;            gum = &gr[g * 10]; }
        else         { base = 1100 + (g - 100) * 10; gum = &gr[1000 + (g - 100) * 10]; }

        int am = 0;
        double best = -1e300, second = -1e300;
        #pragma unroll
        for (int m = 0; m < 10; ++m) {
            const double v = (double)xr[base + m] + (double)gum[m];
            if (v > best) { second = best; best = v; am = m; }
            else if (v > second) second = v;
        }
        if (g < 100) xr[base - 1] = tanhf(xr[base - 1]);
        #pragma unroll
        for (int m = 0; m < 10; ++m) xr[base + m] = (m == am) ? 1.0f : 0.0f;

        if (best - second < THETA) {
            const int p = atomicAdd(cnt, 1);
            if (p < FCAP) list[p] = (row << 8) | g;
        }
    }
    __syncthreads();

    float4* ox = (float4*)(x + (size_t)row * DOUTN);
    #pragma unroll 3
    for (int i = t; i < 525; i += 256) ox[i] = ((float4*)xr)[i];
}

// ---------------------------------------------------------------------------
// f64 fallback: grid-stride over flagged (row,group); exact recompute.
// ---------------------------------------------------------------------------
__global__ __launch_bounds__(256) void fallback_k(
    const float* __restrict__ z,   const float* __restrict__ c,
    const float* __restrict__ W1,  const float* __restrict__ b1,
    const float* __restrict__ W2,  const float* __restrict__ b2,
    const float* __restrict__ Wout,const float* __restrict__ bout,
    const double* __restrict__ sc1,const double* __restrict__ sh1,
    const double* __restrict__ sc2,const double* __restrict__ sh2,
    const float* __restrict__ gc,  const float* __restrict__ gd,
    const int* __restrict__ cnt,   const int* __restrict__ list,
    float* __restrict__ x)
{
    int nf = *cnt;
    if (nf > FCAP) nf = FCAP;
    const int t = threadIdx.x;
    __shared__ double s1[HDIM], s2[HDIM], lg[16];

    for (int fi = blockIdx.x; fi < nf; fi += gridDim.x) {
        const int f   = list[fi];
        const int row = f >> 8, g = f & 255;

        double a = (double)b1[t];
        for (int k = 0; k < DIN; ++k) {
            const double iv = (k < 128) ? (double)z[(size_t)row * 128 + k]
                                        : (double)c[(size_t)row * 100 + k - 128];
            a = fma(iv, (double)W1[(size_t)k * HDIM + t], a);
        }
        const double v1 = fma(a, sc1[t], sh1[t]);
        s1[t] = v1 > 0.0 ? v1 : 0.0;
        __syncthreads();

        double a2 = (double)b2[t];
        for (int k = 0; k < HDIM; ++k)
            a2 = fma(s1[k], (double)W2[(size_t)k * HDIM + t], a2);
        for (int k = 0; k < DIN; ++k) {
            const double iv = (k < 128) ? (double)z[(size_t)row * 128 + k]
                                        : (double)c[(size_t)row * 100 + k - 128];
            a2 = fma(iv, (double)W2[(size_t)(HDIM + k) * HDIM + t], a2);
        }
        const double v2 = fma(a2, sc2[t], sh2[t]);
        s2[t] = v2 > 0.0 ? v2 : 0.0;
        __syncthreads();

        if (t < 10) {
            const int col = (g < 100) ? g * 11 + 1 + t : 1100 + (g - 100) * 10 + t;
            double d = (double)bout[col];
            for (int k = 0; k < HDIM; ++k)
                d = fma(s2[k], (double)Wout[(size_t)k * DOUTN + col], d);
            const double gv = (g < 100) ? (double)gc[((size_t)row * 100 + g) * 10 + t]
                                        : (double)gd[((size_t)row * 100 + (g - 100)) * 10 + t];
            lg[t] = d + gv;
        }
        __syncthreads();

        if (t == 0) {
            int am = 0;
            double best = lg[0];
            #pragma unroll
            for (int m = 1; m < 10; ++m)
                if (lg[m] > best) { best = lg[m]; am = m; }
            const size_t base = (g < 100) ? (size_t)row * DOUTN + (size_t)g * 11 + 1
                                          : (size_t)row * DOUTN + 1100 + (size_t)(g - 100) * 10;
            #pragma unroll
            for (int m = 0; m < 10; ++m) x[base + m] = (m == am) ? 1.0f : 0.0f;
        }
        __syncthreads();
    }
}

__global__ void zero_k(int* cnt) { if (threadIdx.x == 0) *cnt = 0; }

// ---------------------------------------------------------------------------
extern "C" void kernel_launch(void* const* d_in, const int* in_sizes, int n_in,
                              void* d_out, int out_size, void* d_ws, size_t ws_size,
                              hipStream_t stream)
{
    (void)in_sizes; (void)n_in; (void)out_size; (void)ws_size;

    const float* z    = (const float*)d_in[0];
    const float* c    = (const float*)d_in[1];
    const float* W1   = (const float*)d_in[2];
    const float* b1   = (const float*)d_in[3];
    const float* g1   = (const float*)d_in[4];
    const float* be1  = (const float*)d_in[5];
    const float* W2   = (const float*)d_in[6];
    const float* b2   = (const float*)d_in[7];
    const float* g2   = (const float*)d_in[8];
    const float* be2  = (const float*)d_in[9];
    const float* Wout = (const float*)d_in[10];
    const float* bout = (const float*)d_in[11];
    const float* gc   = (const float*)d_in[12];
    const float* gd   = (const float*)d_in[13];
    float* out = (float*)d_out;

    // ---- workspace layout (f64 -> f32 -> u16 -> int) ----
    char* wp = (char*)d_ws;
    double* part = (double*)wp;            wp += 256 * 512 * 8;     // 1 MB
    double* sc1 = (double*)wp;             wp += 256 * 8;
    double* sh1 = (double*)wp;             wp += 256 * 8;
    double* sc2 = (double*)wp;             wp += 256 * 8;
    double* sh2 = (double*)wp;             wp += 256 * 8;
    float* scf1 = (float*)wp;              wp += 256 * 4;
    float* shf1 = (float*)wp;              wp += 256 * 4;
    float* scf2 = (float*)wp;              wp += 256 * 4;
    float* shf2 = (float*)wp;              wp += 256 * 4;
    float* h1   = (float*)wp;              wp += (size_t)BATCH * 256 * 4;  // 16 MB
    float* h2   = (float*)wp;              wp += (size_t)BATCH * 256 * 4;  // 16 MB
    u16* A2hi   = (u16*)wp;                wp += (size_t)BATCH * 256 * 2;  // 8 MB
    u16* A2lo   = (u16*)wp;                wp += (size_t)BATCH * 256 * 2;  // 8 MB
    u16* Wothi  = (u16*)wp;                wp += 2176 * 256 * 2;
    u16* Wotlo  = (u16*)wp;                wp += 2176 * 256 * 2;
    int* cnt    = (int*)wp;                wp += 128;
    int* list   = (int*)wp;

    const dim3 blk(256);
    const dim3 gridH(2, BATCH / 128);    // (2, 128)
    const dim3 gridO(17, BATCH / 128);   // (17, 128)

    zero_k<<<dim3(1), dim3(64), 0, stream>>>(cnt);

    // layers 1-2: f32 path (stat precision)
    gemm_f32<0><<<gridH, blk, 0, stream>>>(z, c, nullptr, nullptr, nullptr, W1, b1, h1);
    colsum2_k<<<dim3(256), blk, 0, stream>>>(h1, part);
    fin_k<<<dim3(1), blk, 0, stream>>>(part, g1, be1, sc1, sh1, scf1, shf1);

    gemm_f32<1><<<gridH, blk, 0, stream>>>(z, c, h1, scf1, shf1, W2, b2, h2);
    colsum2_k<<<dim3(256), blk, 0, stream>>>(h2, part);
    fin_k<<<dim3(1), blk, 0, stream>>>(part, g2, be2, sc2, sh2, scf2, shf2);

    // mode-2: MFMA bf16x3 (proven R5/R6)
    bnsplit_k<<<dim3(BATCH / 4), blk, 0, stream>>>(h2, scf2, shf2, A2hi, A2lo);
    splitW_k<<<dim3(9), blk, 0, stream>>>(Wout, 256, DOUTN, 256, 2176, Wothi, Wotlo);
    gemm_bf16x3<256><<<gridO, blk, 0, stream>>>(A2hi, A2lo, Wothi, Wotlo, bout, out, DOUTN);

    // heads (LDS-staged) + f64 fallback net
    heads2_k<<<dim3(BATCH), blk, 0, stream>>>(out, gc, gd, cnt, list);
    fallback_k<<<dim3(4096), blk, 0, stream>>>(z, c, W1, b1, W2, b2, Wout, bout,
                                               sc1, sh1, sc2, sh2, gc, gd, cnt, list, out);
}

// Round 8
// 425.934 us; speedup vs baseline: 1.9328x; 1.0398x over previous
//
#include <hip/hip_runtime.h>
#include <math.h>

#define BATCH 16384
#define HDIM  256
#define DIN   228    // 128 latent + 100 cond
#define DOUTN 2100
#define NGRP  200
#define THETA 2.5e-4 // top-2 gap below this -> f64 recompute (~2.8k flags, 20-sigma net)
#define FCAP  65536

typedef unsigned short u16;
typedef __attribute__((ext_vector_type(8))) short bf16x8;
typedef __attribute__((ext_vector_type(4))) float f32x4;
typedef __attribute__((ext_vector_type(8))) unsigned short u16x8;
typedef __attribute__((ext_vector_type(4))) unsigned short u16x4;

// RNE split: x = hi + lo (both bf16)
__device__ __forceinline__ void split_bf16(float x, u16& hi, u16& lo) {
    unsigned int u = __float_as_uint(x);
    unsigned int r = (u + 0x7fffu + ((u >> 16) & 1u)) >> 16;
    hi = (u16)r;
    const float hf = __uint_as_float(r << 16);
    const float l = x - hf;
    unsigned int u2 = __float_as_uint(l);
    unsigned int r2 = (u2 + 0x7fffu + ((u2 >> 16) & 1u)) >> 16;
    lo = (u16)r2;
}

// ---------------------------------------------------------------------------
// f32 tiled GEMM, layers 1-2. 64x64 block tile (4 blocks/CU -> 4 waves/SIMD,
// fixes the 1-wave/SIMD latency stall of the 128x128 version), KT=16,
// 256 threads, 4x4 microtile. Same KT-chunked k-order as R7 -> h bit-identical.
// MODE 0: h1 = i0 @ W1 + b1   MODE 1: h2 = [bnrelu(h1), i0] @ W2 + b2
// ---------------------------------------------------------------------------
template <int MODE>
__global__ __launch_bounds__(256) void gemm_f32(
    const float* __restrict__ z,   const float* __restrict__ c,
    const float* __restrict__ hin,
    const float* __restrict__ scf, const float* __restrict__ shf,
    const float* __restrict__ W,   const float* __restrict__ bias,
    float* __restrict__ out)
{
    constexpr int K  = (MODE == 0) ? DIN : (HDIM + DIN);
    constexpr int N  = HDIM;
    constexpr int KT = 16, BM = 64, BN = 64;

    __shared__ float Ash[KT][BM + 4];
    __shared__ float Bsh[KT][BN + 4];

    const int tid  = threadIdx.x;
    const int row0 = blockIdx.y * BM;
    const int n0   = blockIdx.x * BN;
    const int tx   = tid & 15, ty = tid >> 4;
    const int arow = tid >> 2, aq = (tid & 3) * 4;   // A stage: row, k-quarter
    const int bkk  = tid >> 4, bc = (tid & 15) * 4;  // B stage: k, col base

    float acc[4][4] = {};

    for (int kt = 0; kt < K; kt += KT) {
        __syncthreads();
        // ---- A stage (4 elems/thread) ----
        #pragma unroll
        for (int q = 0; q < 4; ++q) {
            const int gk = kt + aq + q;
            float v = 0.f;
            if (MODE == 0) {
                if (gk < DIN)
                    v = (gk < 128) ? z[(size_t)(row0 + arow) * 128 + gk]
                                   : c[(size_t)(row0 + arow) * 100 + gk - 128];
            } else {
                if (gk < HDIM) {
                    const float h = hin[(size_t)(row0 + arow) * HDIM + gk];
                    const float s = fmaf(h, scf[gk], shf[gk]);
                    v = s > 0.f ? s : 0.f;
                } else if (gk < HDIM + DIN) {
                    const int k2 = gk - HDIM;
                    v = (k2 < 128) ? z[(size_t)(row0 + arow) * 128 + k2]
                                   : c[(size_t)(row0 + arow) * 100 + k2 - 128];
                }
            }
            Ash[aq + q][arow] = v;
        }
        // ---- B stage (float4/thread) ----
        {
            const int gk = kt + bkk;
            if (gk < K) {
                *reinterpret_cast<float4*>(&Bsh[bkk][bc]) =
                    *reinterpret_cast<const float4*>(&W[(size_t)gk * N + n0 + bc]);
            } else {
                #pragma unroll
                for (int q = 0; q < 4; ++q) Bsh[bkk][bc + q] = 0.f;
            }
        }
        __syncthreads();
        // ---- compute ----
        #pragma unroll
        for (int kk = 0; kk < KT; ++kk) {
            float a[4], b[4];
            *reinterpret_cast<float4*>(a) = *reinterpret_cast<const float4*>(&Ash[kk][ty * 4]);
            *reinterpret_cast<float4*>(b) = *reinterpret_cast<const float4*>(&Bsh[kk][tx * 4]);
            #pragma unroll
            for (int i = 0; i < 4; ++i)
                #pragma unroll
                for (int j = 0; j < 4; ++j)
                    acc[i][j] = fmaf(a[i], b[j], acc[i][j]);
        }
    }

    // ---- epilogue: + bias, float4 store ----
    #pragma unroll
    for (int i = 0; i < 4; ++i) {
        const size_t row = row0 + ty * 4 + i;
        const int n = n0 + tx * 4;
        float4 r;
        r.x = acc[i][0] + bias[n + 0];
        r.y = acc[i][1] + bias[n + 1];
        r.z = acc[i][2] + bias[n + 2];
        r.w = acc[i][3] + bias[n + 3];
        *reinterpret_cast<float4*>(&out[row * N + n]) = r;
    }
}

// ---------------------------------------------------------------------------
// BN stats: fused column sum+sumsq, f64, 256 blocks x 64 rows.
// ---------------------------------------------------------------------------
__global__ __launch_bounds__(256) void colsum2_k(const float* __restrict__ h,
                                                 double* __restrict__ part)
{
    const int col = threadIdx.x;
    const size_t b0 = (size_t)blockIdx.x * 64;
    double s = 0.0, q = 0.0;
    for (int r = 0; r < 64; ++r) {
        const double v = (double)h[(b0 + r) * HDIM + col];
        s += v;
        q = fma(v, v, q);
    }
    part[(size_t)blockIdx.x * 512 + col]       = s;
    part[(size_t)blockIdx.x * 512 + 256 + col] = q;
}

__global__ __launch_bounds__(256) void fin_k(const double* __restrict__ part,
                                             const float* __restrict__ g,
                                             const float* __restrict__ be,
                                             double* __restrict__ sc64,
                                             double* __restrict__ sh64,
                                             float* __restrict__ scf,
                                             float* __restrict__ shf)
{
    const int col = threadIdx.x;
    double s = 0.0, q = 0.0;
    for (int i = 0; i < 256; ++i) {
        s += part[(size_t)i * 512 + col];
        q += part[(size_t)i * 512 + 256 + col];
    }
    const double mu    = s / (double)BATCH;
    const double var   = q / (double)BATCH - mu * mu;
    const double rs    = 1.0 / sqrt(var + 1e-5);
    const double scale = rs * (double)g[col];
    const double shift = (double)be[col] - mu * scale;
    sc64[col] = scale;  sh64[col] = shift;
    scf[col]  = (float)scale;  shf[col] = (float)shift;
}

// ---------------------------------------------------------------------------
// BN+relu+split h2 -> A2 planes [B][256] bf16 hi/lo.
// ---------------------------------------------------------------------------
__global__ __launch_bounds__(256) void bnsplit_k(const float* __restrict__ h,
                                                 const float* __restrict__ scf,
                                                 const float* __restrict__ shf,
                                                 u16* __restrict__ hi, u16* __restrict__ lo)
{
    const int t = blockIdx.x * 256 + threadIdx.x;   // BATCH*64
    const int row = t >> 6, c4 = (t & 63) * 4;
    const float4 v = *(const float4*)&h[(size_t)row * 256 + c4];
    const float vv[4] = {v.x, v.y, v.z, v.w};
    u16x4 H, L;
    #pragma unroll
    for (int j = 0; j < 4; ++j) {
        float s = fmaf(vv[j], scf[c4 + j], shf[c4 + j]);
        s = fmaxf(s, 0.f);
        u16 hh, ll; split_bf16(s, hh, ll);
        H[j] = hh; L[j] = ll;
    }
    *(u16x4*)&hi[(size_t)row * 256 + c4] = H;
    *(u16x4*)&lo[(size_t)row * 256 + c4] = L;
}

// ---------------------------------------------------------------------------
// Transpose + split Wout: [256][2100] f32 -> planes [2176][256] bf16.
// ---------------------------------------------------------------------------
__global__ __launch_bounds__(256) void splitW_k(const float* __restrict__ W,
                                                int K0, int N0, int Kpad, int Npad,
                                                u16* __restrict__ Whi, u16* __restrict__ Wlo)
{
    const int n = blockIdx.x * 256 + threadIdx.x;
    if (n >= Npad) return;
    for (int kb = 0; kb < Kpad; kb += 8) {
        u16x8 H, L;
        #pragma unroll
        for (int j = 0; j < 8; ++j) {
            const int k = kb + j;
            const float x = (k < K0 && n < N0) ? W[(size_t)k * N0 + n] : 0.f;
            u16 h, l; split_bf16(x, h, l);
            H[j] = h; L[j] = l;
        }
        *(u16x8*)&Whi[(size_t)n * Kpad + kb] = H;
        *(u16x8*)&Wlo[(size_t)n * Kpad + kb] = L;
    }
}

// ---------------------------------------------------------------------------
// bf16x3 MFMA GEMM (PROVEN R5-R7): A [M][256], B [2176][256], 128x128 tile.
// Reg-staged LDS, chunk-XOR swizzle identical on write and read.
// ---------------------------------------------------------------------------
template <int K>
__global__ __launch_bounds__(256) void gemm_bf16x3(
    const u16* __restrict__ Ahi, const u16* __restrict__ Alo,
    const u16* __restrict__ Bhi, const u16* __restrict__ Blo,
    const float* __restrict__ bias, float* __restrict__ out, int Nout)
{
    __shared__ __align__(16) u16 lds[4 * 128 * 64];
    u16* Ah = lds;
    u16* Al = lds + 8192;
    u16* Bh = lds + 16384;
    u16* Bl = lds + 24576;

    const int tid  = threadIdx.x;
    const int lane = tid & 63;
    const int w    = tid >> 6;
    const int wm   = (w >> 1) * 64, wn = (w & 1) * 64;
    const int row0 = blockIdx.y * 128, n0 = blockIdx.x * 128;

    const u16* gAh = Ahi + (size_t)row0 * K;
    const u16* gAl = Alo + (size_t)row0 * K;
    const u16* gBh = Bhi + (size_t)n0 * K;
    const u16* gBl = Blo + (size_t)n0 * K;

    f32x4 acc[4][4] = {};

    for (int kc = 0; kc < K; kc += 64) {
        __syncthreads();
        #pragma unroll
        for (int q = 0; q < 4; ++q) {
            const int cidx = q * 256 + tid;
            const int r = cidx >> 3, s = cidx & 7;
            const size_t go = (size_t)r * K + kc + s * 8;
            const int lo = r * 64 + ((s ^ (r & 7)) * 8);
            const u16x8 va = *(const u16x8*)(gAh + go);
            const u16x8 vb = *(const u16x8*)(gAl + go);
            const u16x8 vc = *(const u16x8*)(gBh + go);
            const u16x8 vd = *(const u16x8*)(gBl + go);
            *(u16x8*)(Ah + lo) = va;
            *(u16x8*)(Al + lo) = vb;
            *(u16x8*)(Bh + lo) = vc;
            *(u16x8*)(Bl + lo) = vd;
        }
        __syncthreads();

        #pragma unroll
        for (int ks = 0; ks < 2; ++ks) {
            bf16x8 ah[4], al[4], bh[4], bl[4];
            const int o = (ks * 4 + (lane >> 4)) * 8;
            #pragma unroll
            for (int mf = 0; mf < 4; ++mf) {
                const int r = wm + mf * 16 + (lane & 15);
                const int off = r * 64 + (o ^ ((r & 7) * 8));
                ah[mf] = *(const bf16x8*)(Ah + off);
                al[mf] = *(const bf16x8*)(Al + off);
            }
            #pragma unroll
            for (int nf = 0; nf < 4; ++nf) {
                const int r = wn + nf * 16 + (lane & 15);
                const int off = r * 64 + (o ^ ((r & 7) * 8));
                bh[nf] = *(const bf16x8*)(Bh + off);
                bl[nf] = *(const bf16x8*)(Bl + off);
            }
            #pragma unroll
            for (int mf = 0; mf < 4; ++mf)
                #pragma unroll
                for (int nf = 0; nf < 4; ++nf) {
                    acc[mf][nf] = __builtin_amdgcn_mfma_f32_16x16x32_bf16(ah[mf], bh[nf], acc[mf][nf], 0, 0, 0);
                    acc[mf][nf] = __builtin_amdgcn_mfma_f32_16x16x32_bf16(ah[mf], bl[nf], acc[mf][nf], 0, 0, 0);
                    acc[mf][nf] = __builtin_amdgcn_mfma_f32_16x16x32_bf16(al[mf], bh[nf], acc[mf][nf], 0, 0, 0);
                }
        }
    }

    const int l4 = lane & 15, lr = lane >> 4;
    #pragma unroll
    for (int nf = 0; nf < 4; ++nf) {
        const int col = n0 + wn + nf * 16 + l4;
        if (col < Nout) {
            const float bv = bias[col];
            #pragma unroll
            for (int mf = 0; mf < 4; ++mf) {
                const int rowb = row0 + wm + mf * 16 + lr * 4;
                #pragma unroll
                for (int r = 0; r < 4; ++r)
                    out[(size_t)(rowb + r) * Nout + col] = acc[mf][nf][r] + bv;
            }
        }
    }
}

// ---------------------------------------------------------------------------
// LDS-staged heads (PROVEN R7): one block per row.
// ---------------------------------------------------------------------------
__global__ __launch_bounds__(256) void heads2_k(float* __restrict__ x,
                                                const float* __restrict__ gc,
                                                const float* __restrict__ gd,
                                                int* __restrict__ cnt,
                                                int* __restrict__ list)
{
    __shared__ __align__(16) float xr[DOUTN];
    __shared__ __align__(16) float gr[2000];

    const int row = blockIdx.x;
    const int t   = threadIdx.x;

    const float4* gx = (const float4*)(x + (size_t)row * DOUTN);
    const float4* ggc = (const float4*)(gc + (size_t)row * 1000);
    const float4* ggd = (const float4*)(gd + (size_t)row * 1000);
    #pragma unroll 3
    for (int i = t; i < 525; i += 256) ((float4*)xr)[i] = gx[i];
    for (int i = t; i < 250; i += 256) ((float4*)gr)[i] = ggc[i];
    for (int i = t; i < 250; i += 256) ((float4*)(gr + 1000))[i] = ggd[i];
    __syncthreads();

    if (t < NGRP) {
        const int g = t;
        int base;
        const float* gum;
        if (g < 100) { base = g * 11 + 1;            gum = &gr[g * 10]; }
        else         { base = 1100 + (g - 100) * 10; gum = &gr[1000 + (g - 100) * 10]; }

        int am = 0;
        double best = -1e300, second = -1e300;
        #pragma unroll
        for (int m = 0; m < 10; ++m) {
            const double v = (double)xr[base + m] + (double)gum[m];
            if (v > best) { second = best; best = v; am = m; }
            else if (v > second) second = v;
        }
        if (g < 100) xr[base - 1] = tanhf(xr[base - 1]);
        #pragma unroll
        for (int m = 0; m < 10; ++m) xr[base + m] = (m == am) ? 1.0f : 0.0f;

        if (best - second < THETA) {
            const int p = atomicAdd(cnt, 1);
            if (p < FCAP) list[p] = (row << 8) | g;
        }
    }
    __syncthreads();

    float4* ox = (float4*)(x + (size_t)row * DOUTN);
    #pragma unroll 3
    for (int i = t; i < 525; i += 256) ox[i] = ((float4*)xr)[i];
}

// ---------------------------------------------------------------------------
// f64 fallback: grid-stride over flagged (row,group); exact recompute.
// ---------------------------------------------------------------------------
__global__ __launch_bounds__(256) void fallback_k(
    const float* __restrict__ z,   const float* __restrict__ c,
    const float* __restrict__ W1,  const float* __restrict__ b1,
    const float* __restrict__ W2,  const float* __restrict__ b2,
    const float* __restrict__ Wout,const float* __restrict__ bout,
    const double* __restrict__ sc1,const double* __restrict__ sh1,
    const double* __restrict__ sc2,const double* __restrict__ sh2,
    const float* __restrict__ gc,  const float* __restrict__ gd,
    const int* __restrict__ cnt,   const int* __restrict__ list,
    float* __restrict__ x)
{
    int nf = *cnt;
    if (nf > FCAP) nf = FCAP;
    const int t = threadIdx.x;
    __shared__ double s1[HDIM], s2[HDIM], lg[16];

    for (int fi = blockIdx.x; fi < nf; fi += gridDim.x) {
        const int f   = list[fi];
        const int row = f >> 8, g = f & 255;

        double a = (double)b1[t];
        for (int k = 0; k < DIN; ++k) {
            const double iv = (k < 128) ? (double)z[(size_t)row * 128 + k]
                                        : (double)c[(size_t)row * 100 + k - 128];
            a = fma(iv, (double)W1[(size_t)k * HDIM + t], a);
        }
        const double v1 = fma(a, sc1[t], sh1[t]);
        s1[t] = v1 > 0.0 ? v1 : 0.0;
        __syncthreads();

        double a2 = (double)b2[t];
        for (int k = 0; k < HDIM; ++k)
            a2 = fma(s1[k], (double)W2[(size_t)k * HDIM + t], a2);
        for (int k = 0; k < DIN; ++k) {
            const double iv = (k < 128) ? (double)z[(size_t)row * 128 + k]
                                        : (double)c[(size_t)row * 100 + k - 128];
            a2 = fma(iv, (double)W2[(size_t)(HDIM + k) * HDIM + t], a2);
        }
        const double v2 = fma(a2, sc2[t], sh2[t]);
        s2[t] = v2 > 0.0 ? v2 : 0.0;
        __syncthreads();

        if (t < 10) {
            const int col = (g < 100) ? g * 11 + 1 + t : 1100 + (g - 100) * 10 + t;
            double d = (double)bout[col];
            for (int k = 0; k < HDIM; ++k)
                d = fma(s2[k], (double)Wout[(size_t)k * DOUTN + col], d);
            const double gv = (g < 100) ? (double)gc[((size_t)row * 100 + g) * 10 + t]
                                        : (double)gd[((size_t)row * 100 + (g - 100)) * 10 + t];
            lg[t] = d + gv;
        }
        __syncthreads();

        if (t == 0) {
            int am = 0;
            double best = lg[0];
            #pragma unroll
            for (int m = 1; m < 10; ++m)
                if (lg[m] > best) { best = lg[m]; am = m; }
            const size_t base = (g < 100) ? (size_t)row * DOUTN + (size_t)g * 11 + 1
                                          : (size_t)row * DOUTN + 1100 + (size_t)(g - 100) * 10;
            #pragma unroll
            for (int m = 0; m < 10; ++m) x[base + m] = (m == am) ? 1.0f : 0.0f;
        }
        __syncthreads();
    }
}

__global__ void zero_k(int* cnt) { if (threadIdx.x == 0) *cnt = 0; }

// ---------------------------------------------------------------------------
extern "C" void kernel_launch(void* const* d_in, const int* in_sizes, int n_in,
                              void* d_out, int out_size, void* d_ws, size_t ws_size,
                              hipStream_t stream)
{
    (void)in_sizes; (void)n_in; (void)out_size; (void)ws_size;

    const float* z    = (const float*)d_in[0];
    const float* c    = (const float*)d_in[1];
    const float* W1   = (const float*)d_in[2];
    const float* b1   = (const float*)d_in[3];
    const float* g1   = (const float*)d_in[4];
    const float* be1  = (const float*)d_in[5];
    const float* W2   = (const float*)d_in[6];
    const float* b2   = (const float*)d_in[7];
    const float* g2   = (const float*)d_in[8];
    const float* be2  = (const float*)d_in[9];
    const float* Wout = (const float*)d_in[10];
    const float* bout = (const float*)d_in[11];
    const float* gc   = (const float*)d_in[12];
    const float* gd   = (const float*)d_in[13];
    float* out = (float*)d_out;

    // ---- workspace layout (f64 -> f32 -> u16 -> int) ----
    char* wp = (char*)d_ws;
    double* part = (double*)wp;            wp += 256 * 512 * 8;     // 1 MB
    double* sc1 = (double*)wp;             wp += 256 * 8;
    double* sh1 = (double*)wp;             wp += 256 * 8;
    double* sc2 = (double*)wp;             wp += 256 * 8;
    double* sh2 = (double*)wp;             wp += 256 * 8;
    float* scf1 = (float*)wp;              wp += 256 * 4;
    float* shf1 = (float*)wp;              wp += 256 * 4;
    float* scf2 = (float*)wp;              wp += 256 * 4;
    float* shf2 = (float*)wp;              wp += 256 * 4;
    float* h1   = (float*)wp;              wp += (size_t)BATCH * 256 * 4;  // 16 MB
    float* h2   = (float*)wp;              wp += (size_t)BATCH * 256 * 4;  // 16 MB
    u16* A2hi   = (u16*)wp;                wp += (size_t)BATCH * 256 * 2;  // 8 MB
    u16* A2lo   = (u16*)wp;                wp += (size_t)BATCH * 256 * 2;  // 8 MB
    u16* Wothi  = (u16*)wp;                wp += 2176 * 256 * 2;
    u16* Wotlo  = (u16*)wp;                wp += 2176 * 256 * 2;
    int* cnt    = (int*)wp;                wp += 128;
    int* list   = (int*)wp;

    const dim3 blk(256);
    const dim3 gridH(4, BATCH / 64);     // (4, 256) = 1024 blocks
    const dim3 gridO(17, BATCH / 128);   // (17, 128)

    zero_k<<<dim3(1), dim3(64), 0, stream>>>(cnt);

    // layers 1-2: f32 path (stat precision), 64x64 tiles for occupancy
    gemm_f32<0><<<gridH, blk, 0, stream>>>(z, c, nullptr, nullptr, nullptr, W1, b1, h1);
    colsum2_k<<<dim3(256), blk, 0, stream>>>(h1, part);
    fin_k<<<dim3(1), blk, 0, stream>>>(part, g1, be1, sc1, sh1, scf1, shf1);

    gemm_f32<1><<<gridH, blk, 0, stream>>>(z, c, h1, scf1, shf1, W2, b2, h2);
    colsum2_k<<<dim3(256), blk, 0, stream>>>(h2, part);
    fin_k<<<dim3(1), blk, 0, stream>>>(part, g2, be2, sc2, sh2, scf2, shf2);

    // mode-2: MFMA bf16x3 (proven R5-R7)
    bnsplit_k<<<dim3(BATCH / 4), blk, 0, stream>>>(h2, scf2, shf2, A2hi, A2lo);
    splitW_k<<<dim3(9), blk, 0, stream>>>(Wout, 256, DOUTN, 256, 2176, Wothi, Wotlo);
    gemm_bf16x3<256><<<gridO, blk, 0, stream>>>(A2hi, A2lo, Wothi, Wotlo, bout, out, DOUTN);

    // heads (LDS-staged) + f64 fallback net
    heads2_k<<<dim3(BATCH), blk, 0, stream>>>(out, gc, gd, cnt, list);
    fallback_k<<<dim3(4096), blk, 0, stream>>>(z, c, W1, b1, W2, b2, Wout, bout,
                                               sc1, sh1, sc2, sh2, gc, gd, cnt, list, out);
}